// Round 4
// baseline (1849.302 us; speedup 1.0000x reference)
//
#include <hip/hip_runtime.h>
#include <math.h>

// Sizes fixed by the problem
#define BATCH 128
#define TT 512      // time steps
#define CIN 512
#define HID 256
#define GG 1024     // 4*HID

typedef _Float16 half2_t __attribute__((ext_vector_type(2)));
typedef _Float16 half8_t __attribute__((ext_vector_type(8)));
typedef float f32x4_t __attribute__((ext_vector_type(4)));

__device__ __forceinline__ float sigf(float x) { return 1.f / (1.f + __expf(-x)); }
__device__ __forceinline__ float tanhf_(float x) {
    float a = fabsf(x);
    float e = __expf(-2.f * a);
    float r = (1.f - e) / (1.f + e);
    return copysignf(r, x);
}
__device__ __forceinline__ float fdot2_(half2_t a, half2_t b, float c) {
#if __has_builtin(__builtin_amdgcn_fdot2)
    return __builtin_amdgcn_fdot2(a, b, c, false);
#else
    return c + (float)a.x * (float)b.x + (float)a.y * (float)b.y;
#endif
}
// quad_perm XOR-add for the 4-lane reduce (VALU pipe, no LDS).
// CTRL must be an immediate for __builtin_amdgcn_update_dpp -> template param.
template <int CTRL>
__device__ __forceinline__ float qadd(float v) {
    int i = __builtin_bit_cast(int, v);
    int j = __builtin_amdgcn_update_dpp(i, i, CTRL, 0xF, 0xF, true);
    return v + __builtin_bit_cast(float, j);
}

// Prep: cast w1/w2 to f16; build PERMUTED wihh (row g'=s*4+j <- w_ih row j*256+s)
// so xg columns land gate-interleaved (scan lane tid reads xg[t][tid], coalesced);
// bsum permuted to match; pack o-gate whh rows into wop[kk][sq][8] f16 (128 KB,
// L2-resident stream for the scan). grid 1024x256.
__global__ void prep_cast(const float* __restrict__ w1, const float* __restrict__ w2,
                          const float* __restrict__ wih, const float* __restrict__ bih,
                          const float* __restrict__ bhh, const float* __restrict__ whh,
                          _Float16* __restrict__ w1h, _Float16* __restrict__ w2h,
                          _Float16* __restrict__ wihh, float* __restrict__ bsum,
                          _Float16* __restrict__ wop)
{
    const int i = blockIdx.x * 256 + threadIdx.x;
    if (i < 131072) w1h[i] = (_Float16)w1[i];
    if (i < 65536)  w2h[i] = (_Float16)w2[i];
    if (i < 262144) {           // permuted cast: row g' = s*4+j <- j*256+s
        const int r = i >> 8, col = i & 255;
        const int j = r & 3, s = r >> 2;
        wihh[i] = (_Float16)wih[(size_t)(j * 256 + s) * 256 + col];
    }
    if (i < 1024) {
        const int j = i & 3, s = i >> 2;
        bsum[i] = bih[j * 256 + s] + bhh[j * 256 + s];
    }
    if (i < 65536) {            // wop[kk][sq][e]: o-row 768+s, k = q4*64+kk*8+e
        const int e = i & 7, sq = (i >> 3) & 1023, kk = i >> 13;
        const int s = sq >> 2, q4 = sq & 3;
        wop[i] = (_Float16)whh[(size_t)(768 + s) * 256 + q4 * 64 + kk * 8 + e];
    }
}

// x[b][c=512][t=512] fp32 -> xt[b][t][c] f16 (64x64 LDS tiles, coalesced both sides)
__global__ __launch_bounds__(256) void cast_transpose_x(
    const float* __restrict__ x, _Float16* __restrict__ xt)
{
    const int b = blockIdx.z, c0 = blockIdx.y * 64, t0 = blockIdx.x * 64;
    __shared__ float tl[64][68];
    const float* xb = x + (size_t)b * CIN * TT;
    const int tid = threadIdx.x;
    const int lt = (tid & 15) * 4, lc = tid >> 4;
    #pragma unroll
    for (int r = 0; r < 4; ++r) {
        const int c = lc + r * 16;
        float4 v = *(const float4*)(xb + (size_t)(c0 + c) * TT + t0 + lt);
        tl[c][lt] = v.x; tl[c][lt + 1] = v.y; tl[c][lt + 2] = v.z; tl[c][lt + 3] = v.w;
    }
    __syncthreads();
    const int trow = tid >> 2, coff = (tid & 3) * 16;
    _Float16 o[16];
    #pragma unroll
    for (int i = 0; i < 16; ++i) o[i] = (_Float16)tl[coff + i][trow];
    _Float16* dst = xt + (size_t)b * TT * CIN + (size_t)(t0 + trow) * CIN + c0 + coff;
    *(float4*)dst = *(float4*)&o[0];
    *(float4*)(dst + 8) = *(float4*)&o[8];
}

// C[M,N](f16) = op( A[M,K]f16 . B[N,K]f16^T + bias ), K%32==0, M%128==0, N%128==0.
// 128x128 tile, 256 thr = 4 waves of 64x64, v_mfma_f32_16x16x32_f16.
template <int RELU, int BIASROW>
__global__ __launch_bounds__(256, 4) void mfma_nt(
    const _Float16* __restrict__ A, const _Float16* __restrict__ B,
    const float* __restrict__ bias, _Float16* __restrict__ C,
    int M, int N, int K, long sA, long sB, long sC)
{
    __shared__ __align__(16) char smem[34816];
    _Float16 (*As)[40] = (_Float16(*)[40])smem;
    _Float16 (*Bs)[40] = (_Float16(*)[40])(smem + 10240);
    float (*Ct)[132] = (float(*)[132])smem;   // 64 x 132 fp32 (union w/ stage)

    const int nb = blockIdx.z;
    A += (size_t)nb * sA; B += (size_t)nb * sB; C += (size_t)nb * sC;
    const int m0 = blockIdx.y * 128, n0 = blockIdx.x * 128;
    const int tid = threadIdx.x;
    const int wave = tid >> 6, lane = tid & 63;
    const int quad = lane >> 4, l15 = lane & 15;
    const int wm = (wave >> 1) * 64, wn = (wave & 1) * 64;
    const int srow = tid >> 1, sko = (tid & 1) * 16;   // staging map

    f32x4_t acc[4][4];
    const f32x4_t zz = {0.f, 0.f, 0.f, 0.f};
    #pragma unroll
    for (int i = 0; i < 4; ++i)
        #pragma unroll
        for (int j = 0; j < 4; ++j) acc[i][j] = zz;

    for (int k0 = 0; k0 < K; k0 += 32) {
        {   // stage A,B tiles: 128 rows x 32 k each; thread = 16 f16 per tile
            const float4* ga = (const float4*)(A + (size_t)(m0 + srow) * K + k0 + sko);
            float4 a0 = ga[0], a1 = ga[1];
            const float4* gb = (const float4*)(B + (size_t)(n0 + srow) * K + k0 + sko);
            float4 b0 = gb[0], b1 = gb[1];
            *(float4*)&As[srow][sko] = a0; *(float4*)&As[srow][sko + 8] = a1;
            *(float4*)&Bs[srow][sko] = b0; *(float4*)&Bs[srow][sko + 8] = b1;
        }
        __syncthreads();
        half8_t af[4], bf[4];
        #pragma unroll
        for (int i = 0; i < 4; ++i) af[i] = *(const half8_t*)&As[wm + i * 16 + l15][quad * 8];
        #pragma unroll
        for (int j = 0; j < 4; ++j) bf[j] = *(const half8_t*)&Bs[wn + j * 16 + l15][quad * 8];
        #pragma unroll
        for (int i = 0; i < 4; ++i)
            #pragma unroll
            for (int j = 0; j < 4; ++j)
                acc[i][j] = __builtin_amdgcn_mfma_f32_16x16x32_f16(af[i], bf[j], acc[i][j], 0, 0, 0);
        __syncthreads();
    }

    // epilogue: bounce 64-row halves through LDS (fp32), bias+relu+cvt, coalesced store
    const int trow = tid >> 2, coff = (tid & 3) * 32;
    float bcol[32];
    if (!BIASROW) {
        #pragma unroll
        for (int i = 0; i < 8; ++i)
            *(float4*)&bcol[i * 4] = *(const float4*)&bias[n0 + coff + i * 4];
    }
    #pragma unroll
    for (int p = 0; p < 2; ++p) {
        if (p) __syncthreads();
        if ((wave >> 1) == p) {
            #pragma unroll
            for (int mi = 0; mi < 4; ++mi)
                #pragma unroll
                for (int ni = 0; ni < 4; ++ni)
                    #pragma unroll
                    for (int r = 0; r < 4; ++r)
                        Ct[mi * 16 + quad * 4 + r][wn + ni * 16 + l15] = acc[mi][ni][r];
        }
        __syncthreads();
        float brow = 0.f;
        if (BIASROW) brow = bias[m0 + p * 64 + trow];
        float vv[32];
        #pragma unroll
        for (int i = 0; i < 8; ++i) *(float4*)&vv[i * 4] = *(float4*)&Ct[trow][coff + i * 4];
        _Float16 o[32];
        #pragma unroll
        for (int i = 0; i < 32; ++i) {
            float v = vv[i] + (BIASROW ? brow : bcol[i]);
            if (RELU) v = fmaxf(v, 0.f);
            o[i] = (_Float16)v;
        }
        _Float16* dst = C + (size_t)(m0 + p * 64 + trow) * N + n0 + coff;
        #pragma unroll
        for (int i = 0; i < 4; ++i) *(float4*)(dst + i * 8) = *(float4*)&o[i * 8];
    }
}

// Forward LSTM scan v8: quad-lane layout, one block per batch.
// v7 post-mortem: o-gate LDS stream was bank-conflicted (~2000cy/step), xg
// staging exposed ~900cy HBM latency at phase top, act phase serialized on 4
// waves (~400cy). v8: thread = (s = tid>>2 unit, q4 = tid&3 K-quarter).
//  - i/f/g gate rows (s, s+256, s+512; K-slice 64*q4..+64) in 96 half2 regs.
//  - o-gate streamed from a packed 128KB L2-resident array wop[kk][tid]
//    (16 blocks/XCD share it; consecutive-16B-per-lane loads; asm clobber
//    defeats LICM so loads re-issue per step). LDS pipe freed.
//  - quad reduce via 2 DPP quad_perm adds (VALU): no psh, no act phase, no B1.
//    Every lane redundantly activates its unit (identical arithmetic).
//  - xg: w_ih rows permuted in prep so lane reads xg[t][tid] (coalesced 2B),
//    prefetched 1 step ahead into a register -> latency fully hidden.
//  - h double-buffered in padded LDS slices (hsh[buf][q4][72]: 4 q4-addresses
//    hit 4 distinct bank groups -> conflict-free broadcast reads). ONE
//    barrier/step.
__global__ __launch_bounds__(1024, 4) void lstm_scan8(
    const _Float16* __restrict__ xg, const float* __restrict__ whh,
    const _Float16* __restrict__ wop, float* __restrict__ out)
{
    __shared__ __align__(16) _Float16 hsh[2][4][72];   // padded: slice stride 144B

    const int tid = threadIdx.x;
    const int b = blockIdx.x;
    const int s = tid >> 2, q4 = tid & 3;
    const _Float16* xgb = xg + (size_t)b * TT * GG;

    // i/f/g weights -> 96 half2 regs (rows s, s+256, s+512; cols 64*q4..+64)
    half2_t wI[32], wF[32], wG[32];
    {
        const float4* pi = (const float4*)(whh + (size_t)s * 256 + q4 * 64);
        const float4* pf = (const float4*)(whh + (size_t)(s + 256) * 256 + q4 * 64);
        const float4* pg = (const float4*)(whh + (size_t)(s + 512) * 256 + q4 * 64);
        #pragma unroll
        for (int k = 0; k < 16; ++k) {
            const float4 a = pi[k];
            wI[2 * k + 0] = half2_t{(_Float16)a.x, (_Float16)a.y};
            wI[2 * k + 1] = half2_t{(_Float16)a.z, (_Float16)a.w};
            const float4 f = pf[k];
            wF[2 * k + 0] = half2_t{(_Float16)f.x, (_Float16)f.y};
            wF[2 * k + 1] = half2_t{(_Float16)f.z, (_Float16)f.w};
            const float4 g = pg[k];
            wG[2 * k + 0] = half2_t{(_Float16)g.x, (_Float16)g.y};
            wG[2 * k + 1] = half2_t{(_Float16)g.z, (_Float16)g.w};
        }
    }
    if (tid < 288) ((unsigned int*)hsh)[tid] = 0u;     // h(0) = 0 (both buffers)
    _Float16 xn = xgb[tid];                            // xg[0][tid] prefetch
    float c = 0.f, hv_out = 0.f;
    __syncthreads();

    unsigned long long wopa = (unsigned long long)(const char*)wop
                            + (unsigned long long)tid * 16u;
    for (int t = 0; t < TT; ++t) {
        asm volatile("" : "+v"(wopa));                 // defeat LICM on o-loads
        const char* wopc = (const char*)wopa;
        // prefetch xg[t+1][tid]; consumed next iteration (~1 step of slack)
        const int tn = (t + 1 < TT) ? t + 1 : t;
        const _Float16 xn_next = xgb[(size_t)tn * GG + tid];

        float aI0 = 0.f, aI1 = 0.f, aF0 = 0.f, aF1 = 0.f;
        float aG0 = 0.f, aG1 = 0.f, aO0 = 0.f, aO1 = 0.f;
        const float4* hp = (const float4*)&hsh[t & 1][q4][0];
        #pragma unroll
        for (int hh2 = 0; hh2 < 2; ++hh2) {            // two half-phases of K
            float4 olv[4];
            #pragma unroll
            for (int i2 = 0; i2 < 4; ++i2)             // issue 4 o-loads (L2)
                olv[i2] = *(const float4*)(wopc + (size_t)(hh2 * 4 + i2) * 16384);
            #pragma unroll
            for (int kk2 = 0; kk2 < 4; ++kk2) {        // i/f/g dots (covers L2 lat)
                const int kk = hh2 * 4 + kk2;
                const float4 hv = hp[kk];              // 4-addr broadcast read
                const half2_t h0 = __builtin_bit_cast(half2_t, hv.x);
                const half2_t h1 = __builtin_bit_cast(half2_t, hv.y);
                const half2_t h2 = __builtin_bit_cast(half2_t, hv.z);
                const half2_t h3 = __builtin_bit_cast(half2_t, hv.w);
                aI0 = fdot2_(wI[4 * kk + 0], h0, aI0);
                aF0 = fdot2_(wF[4 * kk + 0], h0, aF0);
                aG0 = fdot2_(wG[4 * kk + 0], h0, aG0);
                aI1 = fdot2_(wI[4 * kk + 1], h1, aI1);
                aF1 = fdot2_(wF[4 * kk + 1], h1, aF1);
                aG1 = fdot2_(wG[4 * kk + 1], h1, aG1);
                aI0 = fdot2_(wI[4 * kk + 2], h2, aI0);
                aF0 = fdot2_(wF[4 * kk + 2], h2, aF0);
                aG0 = fdot2_(wG[4 * kk + 2], h2, aG0);
                aI1 = fdot2_(wI[4 * kk + 3], h3, aI1);
                aF1 = fdot2_(wF[4 * kk + 3], h3, aF1);
                aG1 = fdot2_(wG[4 * kk + 3], h3, aG1);
            }
            #pragma unroll
            for (int kk2 = 0; kk2 < 4; ++kk2) {        // o dots (weights landed)
                const int kk = hh2 * 4 + kk2;
                const float4 hv = hp[kk];              // cheap broadcast re-read
                const float4 wv = olv[kk2];
                aO0 = fdot2_(__builtin_bit_cast(half2_t, wv.x),
                             __builtin_bit_cast(half2_t, hv.x), aO0);
                aO1 = fdot2_(__builtin_bit_cast(half2_t, wv.y),
                             __builtin_bit_cast(half2_t, hv.y), aO1);
                aO0 = fdot2_(__builtin_bit_cast(half2_t, wv.z),
                             __builtin_bit_cast(half2_t, hv.z), aO0);
                aO1 = fdot2_(__builtin_bit_cast(half2_t, wv.w),
                             __builtin_bit_cast(half2_t, hv.w), aO1);
            }
        }
        float aI = aI0 + aI1, aF = aF0 + aF1, aG = aG0 + aG1, aO = aO0 + aO1;
        // add xg (lane's element = gate q4 of unit s), then quad-reduce
        const float xv = (float)xn;
        aI += (q4 == 0) ? xv : 0.f;
        aF += (q4 == 1) ? xv : 0.f;
        aG += (q4 == 2) ? xv : 0.f;
        aO += (q4 == 3) ? xv : 0.f;
        aI = qadd<0x4E>(qadd<0xB1>(aI));               // XOR-1 then XOR-2
        aF = qadd<0x4E>(qadd<0xB1>(aF));
        aG = qadd<0x4E>(qadd<0xB1>(aG));
        aO = qadd<0x4E>(qadd<0xB1>(aO));
        // all 4 quad lanes redundantly activate unit s (identical arithmetic)
        const float iv = sigf(aI), fv = sigf(aF), gv = tanhf_(aG), ov = sigf(aO);
        c = fv * c + iv * gv;
        hv_out = ov * tanhf_(c);
        if (q4 == 0) hsh[(t + 1) & 1][s >> 6][s & 63] = (_Float16)hv_out;
        xn = xn_next;
        __syncthreads();                               // ONE barrier per step
    }
    if (q4 == 0) out[(size_t)b * 512 + s] = hv_out;
}

// Backward-direction LSTM last step (h=c=0): needs only seq[:,T-1,:].
__global__ __launch_bounds__(256) void lstm_back_last(
    const _Float16* __restrict__ y2h, const float* __restrict__ wih,
    const float* __restrict__ bih, const float* __restrict__ bhh,
    float* __restrict__ out)
{
    const int b = blockIdx.x;
    const int t = threadIdx.x;
    __shared__ float s[256];
    s[t] = (float)y2h[(size_t)b * (HID * TT) + (TT - 1) * HID + t];
    __syncthreads();
    float acc[4];
    #pragma unroll
    for (int q = 0; q < 4; ++q) acc[q] = bih[t + q * 256] + bhh[t + q * 256];
    #pragma unroll
    for (int q = 0; q < 4; ++q) {
        const float* w = wih + (size_t)(t + q * 256) * 256;
        float a = acc[q];
        for (int k = 0; k < 256; k += 4) {
            const float4 w4 = *(const float4*)&w[k];
            const float4 h4 = *(const float4*)&s[k];
            a += w4.x * h4.x; a += w4.y * h4.y;
            a += w4.z * h4.z; a += w4.w * h4.w;
        }
        acc[q] = a;
    }
    const float i = sigf(acc[0]);
    const float g = tanhf_(acc[2]), o = sigf(acc[3]);
    const float c = i * g;           // c_prev = 0, forget path vanishes
    const float h = o * tanhf_(c);
    out[(size_t)b * 512 + 256 + t] = h;
}

extern "C" void kernel_launch(void* const* d_in, const int* in_sizes, int n_in,
                              void* d_out, int out_size, void* d_ws, size_t ws_size,
                              hipStream_t stream) {
    const float* x      = (const float*)d_in[0];
    const float* w1     = (const float*)d_in[1];
    const float* b1     = (const float*)d_in[2];
    const float* w2     = (const float*)d_in[3];
    const float* b2     = (const float*)d_in[4];
    const float* w_ih_f = (const float*)d_in[5];
    const float* w_hh_f = (const float*)d_in[6];
    const float* b_ih_f = (const float*)d_in[7];
    const float* b_hh_f = (const float*)d_in[8];
    const float* w_ih_b = (const float*)d_in[9];
    // d_in[10] = w_hh_b: provably unused (only first reversed step reaches output)
    const float* b_ih_b = (const float*)d_in[11];
    const float* b_hh_b = (const float*)d_in[12];
    float* out = (float*)d_out;

    // Workspace layout (bytes):
    //   xgh  f16 [65536][1024] :         0 .. 134217728
    //   xt   f16 [128][512][512]: 134217728 .. 201326592
    //   y1t  f16 [128][512][256]: 201326592 .. 234881024   (= y1^T per batch)
    //   y2h  f16 [128][256][512]: 234881024 .. 268435456   (canonical = seq flat)
    //   w1h  f16 131072        : 268435456 .. 268697600
    //   w2h  f16 65536         : 268697600 .. 268828672
    //   wihh f16 262144        : 268828672 .. 269352960   (ROW-PERMUTED g'=s*4+j)
    //   bsum f32 1024          : 269352960 .. 269357056   (permuted to match)
    //   wop  f16 65536         : 269357056 .. 269488128   (packed o-gate, 128KB)
    char* ws = (char*)d_ws;
    _Float16* xgh  = (_Float16*)(ws);
    _Float16* xt   = (_Float16*)(ws + 134217728);
    _Float16* y1t  = (_Float16*)(ws + 201326592);
    _Float16* y2h  = (_Float16*)(ws + 234881024);
    _Float16* w1h  = (_Float16*)(ws + 268435456);
    _Float16* w2h  = (_Float16*)(ws + 268697600);
    _Float16* wihh = (_Float16*)(ws + 268828672);
    float*    bsum = (float*)   (ws + 269352960);
    _Float16* wop  = (_Float16*)(ws + 269357056);

    prep_cast<<<1024, 256, 0, stream>>>(w1, w2, w_ih_f, b_ih_f, b_hh_f, w_hh_f,
                                        w1h, w2h, wihh, bsum, wop);
    cast_transpose_x<<<dim3(8, 8, BATCH), 256, 0, stream>>>(x, xt);
    // conv1: y1t[b][t][m1] = relu( xt[b][t][:] . w1h[m1][:] + b1[m1] )   (bias on col)
    mfma_nt<1, 0><<<dim3(2, 4, BATCH), 256, 0, stream>>>(
        xt, w1h, b1, y1t, 512, 256, 512, 512L * 512, 0, 512L * 256);
    // conv2: y2h[b][m2][t] = relu( w2h[m2][:] . y1t[b][t][:] + b2[m2] )  (bias on row)
    mfma_nt<1, 1><<<dim3(4, 2, BATCH), 256, 0, stream>>>(
        w2h, y1t, b2, y2h, 256, 512, 256, 0, 512L * 256, 256L * 512);
    // xg: xgh[r][g'] = y2h-flat[r][:] . wihh[g'][:] + bsum[g']           (bias on col)
    mfma_nt<0, 0><<<dim3(8, 512, 1), 256, 0, stream>>>(
        y2h, wihh, bsum, xgh, 65536, 1024, 256, 0, 0, 0);
    // backward last step (writes out[:, 256:512))
    lstm_back_last<<<BATCH, 256, 0, stream>>>(y2h, w_ih_b, b_ih_b, b_hh_b, out);
    // forward scan v8: quad-lane, 1 block/batch, 1 barrier/step (writes out[:,0:256))
    lstm_scan8<<<BATCH, 1024, 0, stream>>>(xgh, w_hh_f, wop, out);
}

// Round 5
// 1511.907 us; speedup vs baseline: 1.2232x; 1.2232x over previous
//
#include <hip/hip_runtime.h>
#include <math.h>

// Sizes fixed by the problem
#define BATCH 128
#define TT 512      // time steps
#define CIN 512
#define HID 256
#define GG 1024     // 4*HID

typedef _Float16 half2_t __attribute__((ext_vector_type(2)));
typedef _Float16 half8_t __attribute__((ext_vector_type(8)));
typedef float f32x4_t __attribute__((ext_vector_type(4)));

__device__ __forceinline__ float sigf(float x) { return 1.f / (1.f + __expf(-x)); }
__device__ __forceinline__ float tanhf_(float x) {
    float a = fabsf(x);
    float e = __expf(-2.f * a);
    float r = (1.f - e) / (1.f + e);
    return copysignf(r, x);
}
__device__ __forceinline__ float fdot2_(half2_t a, half2_t b, float c) {
#if __has_builtin(__builtin_amdgcn_fdot2)
    return __builtin_amdgcn_fdot2(a, b, c, false);
#else
    return c + (float)a.x * (float)b.x + (float)a.y * (float)b.y;
#endif
}

// Tiny prep: cast w1/w2/w_ih_f to f16, sum LSTM biases. grid 1024x256.
__global__ void prep_cast(const float* __restrict__ w1, const float* __restrict__ w2,
                          const float* __restrict__ wih, const float* __restrict__ bih,
                          const float* __restrict__ bhh,
                          _Float16* __restrict__ w1h, _Float16* __restrict__ w2h,
                          _Float16* __restrict__ wihh, float* __restrict__ bsum)
{
    const int i = blockIdx.x * 256 + threadIdx.x;
    if (i < 131072) w1h[i] = (_Float16)w1[i];
    if (i < 65536)  w2h[i] = (_Float16)w2[i];
    if (i < 262144) wihh[i] = (_Float16)wih[i];
    if (i < 1024)   bsum[i] = bih[i] + bhh[i];
}

// x[b][c=512][t=512] fp32 -> xt[b][t][c] f16 (64x64 LDS tiles, coalesced both sides)
__global__ __launch_bounds__(256) void cast_transpose_x(
    const float* __restrict__ x, _Float16* __restrict__ xt)
{
    const int b = blockIdx.z, c0 = blockIdx.y * 64, t0 = blockIdx.x * 64;
    __shared__ float tl[64][68];
    const float* xb = x + (size_t)b * CIN * TT;
    const int tid = threadIdx.x;
    const int lt = (tid & 15) * 4, lc = tid >> 4;
    #pragma unroll
    for (int r = 0; r < 4; ++r) {
        const int c = lc + r * 16;
        float4 v = *(const float4*)(xb + (size_t)(c0 + c) * TT + t0 + lt);
        tl[c][lt] = v.x; tl[c][lt + 1] = v.y; tl[c][lt + 2] = v.z; tl[c][lt + 3] = v.w;
    }
    __syncthreads();
    const int trow = tid >> 2, coff = (tid & 3) * 16;
    _Float16 o[16];
    #pragma unroll
    for (int i = 0; i < 16; ++i) o[i] = (_Float16)tl[coff + i][trow];
    _Float16* dst = xt + (size_t)b * TT * CIN + (size_t)(t0 + trow) * CIN + c0 + coff;
    *(float4*)dst = *(float4*)&o[0];
    *(float4*)(dst + 8) = *(float4*)&o[8];
}

// C[M,N](f16) = op( A[M,K]f16 . B[N,K]f16^T + bias ), K%32==0, M%128==0, N%128==0.
// 128x128 tile, 256 thr = 4 waves of 64x64, v_mfma_f32_16x16x32_f16.
// A/B-frag idx=lane&15, k=quad*8+j; D row=quad*4+reg, col=lane&15 (verified).
template <int RELU, int BIASROW>
__global__ __launch_bounds__(256, 4) void mfma_nt(
    const _Float16* __restrict__ A, const _Float16* __restrict__ B,
    const float* __restrict__ bias, _Float16* __restrict__ C,
    int M, int N, int K, long sA, long sB, long sC)
{
    __shared__ __align__(16) char smem[34816];
    _Float16 (*As)[40] = (_Float16(*)[40])smem;
    _Float16 (*Bs)[40] = (_Float16(*)[40])(smem + 10240);
    float (*Ct)[132] = (float(*)[132])smem;   // 64 x 132 fp32 (union w/ stage)

    const int nb = blockIdx.z;
    A += (size_t)nb * sA; B += (size_t)nb * sB; C += (size_t)nb * sC;
    const int m0 = blockIdx.y * 128, n0 = blockIdx.x * 128;
    const int tid = threadIdx.x;
    const int wave = tid >> 6, lane = tid & 63;
    const int quad = lane >> 4, l15 = lane & 15;
    const int wm = (wave >> 1) * 64, wn = (wave & 1) * 64;
    const int srow = tid >> 1, sko = (tid & 1) * 16;   // staging map

    f32x4_t acc[4][4];
    const f32x4_t zz = {0.f, 0.f, 0.f, 0.f};
    #pragma unroll
    for (int i = 0; i < 4; ++i)
        #pragma unroll
        for (int j = 0; j < 4; ++j) acc[i][j] = zz;

    for (int k0 = 0; k0 < K; k0 += 32) {
        {   // stage A,B tiles: 128 rows x 32 k each; thread = 16 f16 per tile
            const float4* ga = (const float4*)(A + (size_t)(m0 + srow) * K + k0 + sko);
            float4 a0 = ga[0], a1 = ga[1];
            const float4* gb = (const float4*)(B + (size_t)(n0 + srow) * K + k0 + sko);
            float4 b0 = gb[0], b1 = gb[1];
            *(float4*)&As[srow][sko] = a0; *(float4*)&As[srow][sko + 8] = a1;
            *(float4*)&Bs[srow][sko] = b0; *(float4*)&Bs[srow][sko + 8] = b1;
        }
        __syncthreads();
        half8_t af[4], bf[4];
        #pragma unroll
        for (int i = 0; i < 4; ++i) af[i] = *(const half8_t*)&As[wm + i * 16 + l15][quad * 8];
        #pragma unroll
        for (int j = 0; j < 4; ++j) bf[j] = *(const half8_t*)&Bs[wn + j * 16 + l15][quad * 8];
        #pragma unroll
        for (int i = 0; i < 4; ++i)
            #pragma unroll
            for (int j = 0; j < 4; ++j)
                acc[i][j] = __builtin_amdgcn_mfma_f32_16x16x32_f16(af[i], bf[j], acc[i][j], 0, 0, 0);
        __syncthreads();
    }

    // epilogue: bounce 64-row halves through LDS (fp32), bias+relu+cvt, coalesced store
    const int trow = tid >> 2, coff = (tid & 3) * 32;
    float bcol[32];
    if (!BIASROW) {
        #pragma unroll
        for (int i = 0; i < 8; ++i)
            *(float4*)&bcol[i * 4] = *(const float4*)&bias[n0 + coff + i * 4];
    }
    #pragma unroll
    for (int p = 0; p < 2; ++p) {
        if (p) __syncthreads();
        if ((wave >> 1) == p) {
            #pragma unroll
            for (int mi = 0; mi < 4; ++mi)
                #pragma unroll
                for (int ni = 0; ni < 4; ++ni)
                    #pragma unroll
                    for (int r = 0; r < 4; ++r)
                        Ct[mi * 16 + quad * 4 + r][wn + ni * 16 + l15] = acc[mi][ni][r];
        }
        __syncthreads();
        float brow = 0.f;
        if (BIASROW) brow = bias[m0 + p * 64 + trow];
        float vv[32];
        #pragma unroll
        for (int i = 0; i < 8; ++i) *(float4*)&vv[i * 4] = *(float4*)&Ct[trow][coff + i * 4];
        _Float16 o[32];
        #pragma unroll
        for (int i = 0; i < 32; ++i) {
            float v = vv[i] + (BIASROW ? brow : bcol[i]);
            if (RELU) v = fmaxf(v, 0.f);
            o[i] = (_Float16)v;
        }
        _Float16* dst = C + (size_t)(m0 + p * 64 + trow) * N + n0 + coff;
        #pragma unroll
        for (int i = 0; i < 4; ++i) *(float4*)(dst + i * 8) = *(float4*)&o[i * 8];
    }
}

// Forward LSTM scan v9 = v5 skeleton + dual-path (L2-fast / MALL-slow) exchange.
// v6/v7/v8 post-mortems: (a) batches were already parallel across blocks, so
// interleaving batches per block only lengthens the critical path; (b) per-CU
// load BW is ~60-100 B/cy -> streaming 1/4 of the weights per step (LDS or L2)
// costs 2000-3000cy/step; weights must be register-resident, forcing the
// 2-block split. So the only remaining lever is the exchange round-trip.
// v5 pairs block g with g+128: under the measured round-robin dispatch
// (XCD = bid % 8) both land on the SAME XCD, whose L2 is shared and coherent.
// sc0 store (write-through L1 -> L2) + sc0 load (bypass L1, hit L2) exchange
// in ~200cy instead of the ~2000cy+ agent-scope MALL round trip.
// Correctness does NOT depend on the mapping: dual-path publish (fast sc0
// buffer + v5's agent-scope buffer); poll tries fast 4x then alternates in
// slow reads. Cross-XCD placement -> fast line is permanently stale (L2 not
// probed), tags never match, everything routes through the proven slow path.
// Fast buffer (xbF) sits in the dead y1t region, zeroed by lstm_back_last
// (after conv2's last y1t read, before this kernel; stream-ordered).
__global__ __launch_bounds__(1024, 4) void lstm_scan9(
    const _Float16* __restrict__ xg, const float* __restrict__ whh,
    float* __restrict__ out, unsigned long long* __restrict__ xb,
    unsigned long long* __restrict__ xbF)
{
    const int tid = threadIdx.x;
    const int bid = blockIdx.x;
    const int is_hi = (bid >= 128) ? 1 : 0;
    const int g = is_hi ? bid - 128 : bid;
    const int q4 = tid >> 8;           // K-quarter (wave-uniform)
    const int s = tid & 255;
    const int u = s & 127;
    const int rowA = (s >> 7) * 256 + is_hi * 128 + u;  // gate 0/1 row
    const int rowB = rowA + 512;                        // gate 2/3 row

    __shared__ __align__(16) unsigned int hsh[128];  // h: 256 f16 (lo|hi)
    __shared__ float psh[2048];                      // [quarter][512 rows]

    half2_t wA[32], wB[32];
    {
        const float4* pa = (const float4*)(whh + (size_t)rowA * 256 + q4 * 64);
        const float4* pb = (const float4*)(whh + (size_t)rowB * 256 + q4 * 64);
        #pragma unroll
        for (int k = 0; k < 16; ++k) {
            float4 a = pa[k], b = pb[k];
            wA[2 * k + 0] = half2_t{(_Float16)a.x, (_Float16)a.y};
            wA[2 * k + 1] = half2_t{(_Float16)a.z, (_Float16)a.w};
            wB[2 * k + 0] = half2_t{(_Float16)b.x, (_Float16)b.y};
            wB[2 * k + 1] = half2_t{(_Float16)b.z, (_Float16)b.w};
        }
    }
    if (tid < 128) hsh[tid] = 0u;
    const _Float16* xgb = xg + (size_t)g * TT * GG;
    float xA = 0.f, xB = 0.f;
    if (q4 == 0) { xA = (float)xgb[rowA]; xB = (float)xgb[rowB]; }
    float c0 = 0.f, c1 = 0.f, hk0 = 0.f, hk1 = 0.f;   // wave-0 lane state
    __syncthreads();

    for (int t = 0; t < TT; ++t) {
        const float vA = xA, vB = xB;
        if (q4 == 0 && t < TT - 1) {   // prefetch next xg behind the dot loop
            xA = (float)xgb[(size_t)(t + 1) * GG + rowA];
            xB = (float)xgb[(size_t)(t + 1) * GG + rowB];
        }
        float aA0 = 0.f, aA1 = 0.f, aB0 = 0.f, aB1 = 0.f;
        const float4* hp = (const float4*)hsh + q4 * 8;
        #pragma unroll
        for (int kk = 0; kk < 8; ++kk) {
            const float4 hv = hp[kk];   // wave-uniform address -> broadcast
            const half2_t h0 = __builtin_bit_cast(half2_t, hv.x);
            const half2_t h1 = __builtin_bit_cast(half2_t, hv.y);
            const half2_t h2 = __builtin_bit_cast(half2_t, hv.z);
            const half2_t h3 = __builtin_bit_cast(half2_t, hv.w);
            aA0 = fdot2_(wA[4 * kk + 0], h0, aA0);
            aA1 = fdot2_(wA[4 * kk + 1], h1, aA1);
            aA0 = fdot2_(wA[4 * kk + 2], h2, aA0);
            aA1 = fdot2_(wA[4 * kk + 3], h3, aA1);
            aB0 = fdot2_(wB[4 * kk + 0], h0, aB0);
            aB1 = fdot2_(wB[4 * kk + 1], h1, aB1);
            aB0 = fdot2_(wB[4 * kk + 2], h2, aB0);
            aB1 = fdot2_(wB[4 * kk + 3], h3, aB1);
        }
        psh[q4 * 512 + s]       = aA0 + aA1 + vA;
        psh[q4 * 512 + 256 + s] = aB0 + aB1 + vB;
        __syncthreads();               // B1: partials staged; h reads done
        if (tid < 64) {                // wave 0 finishes units 2l, 2l+1
            const int l = tid;
            float2 gate[4];
            #pragma unroll
            for (int gg = 0; gg < 4; ++gg) {
                float2 sum = {0.f, 0.f};
                #pragma unroll
                for (int qq = 0; qq < 4; ++qq) {
                    const float2 v = *(const float2*)&psh[qq * 512 + gg * 128 + 2 * l];
                    sum.x += v.x; sum.y += v.y;
                }
                gate[gg] = sum;
            }
            const float i0 = sigf(gate[0].x), i1 = sigf(gate[0].y);
            const float f0 = sigf(gate[1].x), f1 = sigf(gate[1].y);
            const float g0 = tanhf_(gate[2].x), g1 = tanhf_(gate[2].y);
            const float o0 = sigf(gate[3].x), o1 = sigf(gate[3].y);
            c0 = f0 * c0 + i0 * g0;  hk0 = o0 * tanhf_(c0);
            c1 = f1 * c1 + i1 * g1;  hk1 = o1 * tanhf_(c1);
            const unsigned int u0 =
                (unsigned int)__builtin_bit_cast(unsigned short, (_Float16)hk0);
            const unsigned int u1 =
                (unsigned int)__builtin_bit_cast(unsigned short, (_Float16)hk1);
            if (t < TT - 1) {
                const unsigned int tg = (unsigned int)(t + 1) << 16;
                const unsigned long long pk =
                    ((unsigned long long)(tg | u1) << 32) | (unsigned long long)(tg | u0);
                // fast publish: write-through into this XCD's L2 (sc0)
                unsigned long long* fdst = &xbF[((size_t)g * 2 + is_hi) * 64 + l];
                asm volatile("global_store_dwordx2 %0, %1, off sc0"
                             :: "v"(fdst), "v"(pk) : "memory");
                // slow publish: agent scope (MALL) — always-correct fallback
                __hip_atomic_store(&xb[((size_t)g * 2 + is_hi) * 64 + l], pk,
                                   __ATOMIC_RELAXED, __HIP_MEMORY_SCOPE_AGENT);
                asm volatile("" ::: "memory");
                hsh[is_hi * 64 + l] = u0 | (u1 << 16);   // own half into LDS
                const unsigned long long* fsrc =
                    &xbF[((size_t)g * 2 + (1 - is_hi)) * 64 + l];
                const unsigned long long* ssrc =
                    &xb[((size_t)g * 2 + (1 - is_hi)) * 64 + l];
                const unsigned int want = (unsigned int)(t + 1);
                unsigned long long v;
                int spin = 0;
                for (;;) {
                    asm volatile("global_load_dwordx2 %0, %1, off sc0\n\t"
                                 "s_waitcnt vmcnt(0)"
                                 : "=v"(v) : "v"(fsrc) : "memory");
                    if ((((v >> 16) & 0xFFFFu) == want) &&
                        ((unsigned)(v >> 48) == want)) break;
                    if (++spin >= 4) {   // cross-XCD (or late): proven slow path
                        v = __hip_atomic_load(ssrc, __ATOMIC_RELAXED,
                                              __HIP_MEMORY_SCOPE_AGENT);
                        if ((((v >> 16) & 0xFFFFu) == want) &&
                            ((unsigned)(v >> 48) == want)) break;
                        __builtin_amdgcn_s_sleep(1);
                    }
                }
                hsh[(1 - is_hi) * 64 + l] =
                    (unsigned int)(v & 0xFFFFu) |
                    ((unsigned int)((v >> 32) & 0xFFFFu) << 16);
            } else {
                hsh[is_hi * 64 + l] = u0 | (u1 << 16);
            }
        }
        __syncthreads();               // B2: h (own + partner) visible to all
    }
    if (tid < 64) {
        out[(size_t)g * 512 + is_hi * 128 + 2 * tid + 0] = hk0;
        out[(size_t)g * 512 + is_hi * 128 + 2 * tid + 1] = hk1;
    }
}

// Backward-direction LSTM last step (h=c=0): needs only seq[:,T-1,:].
// Also zeroes the fast-exchange buffer xbF (16384 u64 across 32768 threads)
// before lstm_scan9 runs — this region is the dead y1t space.
__global__ __launch_bounds__(256) void lstm_back_last(
    const _Float16* __restrict__ y2h, const float* __restrict__ wih,
    const float* __restrict__ bih, const float* __restrict__ bhh,
    float* __restrict__ out, unsigned long long* __restrict__ xbF)
{
    const int b = blockIdx.x;
    const int t = threadIdx.x;
    const int gi = b * 256 + t;
    if (gi < 16384) xbF[gi] = 0ull;    // tag 0 never matches t+1 in [1,511]
    __shared__ float s[256];
    s[t] = (float)y2h[(size_t)b * (HID * TT) + (TT - 1) * HID + t];
    __syncthreads();
    float acc[4];
    #pragma unroll
    for (int q = 0; q < 4; ++q) acc[q] = bih[t + q * 256] + bhh[t + q * 256];
    #pragma unroll
    for (int q = 0; q < 4; ++q) {
        const float* w = wih + (size_t)(t + q * 256) * 256;
        float a = acc[q];
        for (int k = 0; k < 256; k += 4) {
            const float4 w4 = *(const float4*)&w[k];
            const float4 h4 = *(const float4*)&s[k];
            a += w4.x * h4.x; a += w4.y * h4.y;
            a += w4.z * h4.z; a += w4.w * h4.w;
        }
        acc[q] = a;
    }
    const float i = sigf(acc[0]);
    const float g = tanhf_(acc[2]), o = sigf(acc[3]);
    const float c = i * g;           // c_prev = 0, forget path vanishes
    const float h = o * tanhf_(c);
    out[(size_t)b * 512 + 256 + t] = h;
}

extern "C" void kernel_launch(void* const* d_in, const int* in_sizes, int n_in,
                              void* d_out, int out_size, void* d_ws, size_t ws_size,
                              hipStream_t stream) {
    const float* x      = (const float*)d_in[0];
    const float* w1     = (const float*)d_in[1];
    const float* b1     = (const float*)d_in[2];
    const float* w2     = (const float*)d_in[3];
    const float* b2     = (const float*)d_in[4];
    const float* w_ih_f = (const float*)d_in[5];
    const float* w_hh_f = (const float*)d_in[6];
    const float* b_ih_f = (const float*)d_in[7];
    const float* b_hh_f = (const float*)d_in[8];
    const float* w_ih_b = (const float*)d_in[9];
    // d_in[10] = w_hh_b: provably unused (only first reversed step reaches output)
    const float* b_ih_b = (const float*)d_in[11];
    const float* b_hh_b = (const float*)d_in[12];
    float* out = (float*)d_out;

    // Workspace layout (bytes):
    //   xgh  f16 [65536][1024] :         0 .. 134217728
    //   xt   f16 [128][512][512]: 134217728 .. 201326592
    //   y1t  f16 [128][512][256]: 201326592 .. 234881024   (= y1^T per batch)
    //     (first 131072 B of y1t reused as xbF after conv2 — zeroed in back_last)
    //   y2h  f16 [128][256][512]: 234881024 .. 268435456   (canonical = seq flat)
    //   w1h  f16 131072        : 268435456 .. 268697600
    //   w2h  f16 65536         : 268697600 .. 268828672
    //   wihh f16 262144        : 268828672 .. 269352960
    //   bsum f32 1024          : 269352960 .. 269357056
    //   xb   u64 16384         : 269357056 .. 269488128   (tagged h exchange, MALL)
    char* ws = (char*)d_ws;
    _Float16* xgh  = (_Float16*)(ws);
    _Float16* xt   = (_Float16*)(ws + 134217728);
    _Float16* y1t  = (_Float16*)(ws + 201326592);
    _Float16* y2h  = (_Float16*)(ws + 234881024);
    _Float16* w1h  = (_Float16*)(ws + 268435456);
    _Float16* w2h  = (_Float16*)(ws + 268697600);
    _Float16* wihh = (_Float16*)(ws + 268828672);
    float*    bsum = (float*)   (ws + 269352960);
    unsigned long long* xb  = (unsigned long long*)(ws + 269357056);
    unsigned long long* xbF = (unsigned long long*)(ws + 201326592); // dead y1t

    prep_cast<<<1024, 256, 0, stream>>>(w1, w2, w_ih_f, b_ih_f, b_hh_f,
                                        w1h, w2h, wihh, bsum);
    cast_transpose_x<<<dim3(8, 8, BATCH), 256, 0, stream>>>(x, xt);
    // conv1: y1t[b][t][m1] = relu( xt[b][t][:] . w1h[m1][:] + b1[m1] )   (bias on col)
    mfma_nt<1, 0><<<dim3(2, 4, BATCH), 256, 0, stream>>>(
        xt, w1h, b1, y1t, 512, 256, 512, 512L * 512, 0, 512L * 256);
    // conv2: y2h[b][m2][t] = relu( w2h[m2][:] . y1t[b][t][:] + b2[m2] )  (bias on row)
    mfma_nt<1, 1><<<dim3(4, 2, BATCH), 256, 0, stream>>>(
        w2h, y1t, b2, y2h, 256, 512, 256, 0, 512L * 256, 256L * 512);
    // xg: xgh[r][g] = y2h-flat[r][:] . wihh[g][:] + bsum[g]              (bias on col)
    mfma_nt<0, 0><<<dim3(8, 512, 1), 256, 0, stream>>>(
        y2h, wihh, bsum, xgh, 65536, 1024, 256, 0, 0, 0);
    // backward last step (writes out[:, 256:512)) + zero xbF for the scan
    lstm_back_last<<<BATCH, 256, 0, stream>>>(y2h, w_ih_b, b_ih_b, b_hh_b, out, xbF);
    // forward scan v9 (writes out[:, 0:256))
    lstm_scan9<<<256, 1024, 0, stream>>>(xgh, w_hh_f, out, xb, xbF);
}

// Round 6
// 1452.580 us; speedup vs baseline: 1.2731x; 1.0408x over previous
//
#include <hip/hip_runtime.h>
#include <math.h>

// Sizes fixed by the problem
#define BATCH 128
#define TT 512      // time steps
#define CIN 512
#define HID 256
#define GG 1024     // 4*HID

typedef _Float16 half2_t __attribute__((ext_vector_type(2)));
typedef _Float16 half8_t __attribute__((ext_vector_type(8)));
typedef float f32x4_t __attribute__((ext_vector_type(4)));

__device__ __forceinline__ float sigf(float x) { return 1.f / (1.f + __expf(-x)); }
__device__ __forceinline__ float tanhf_(float x) {
    float a = fabsf(x);
    float e = __expf(-2.f * a);
    float r = (1.f - e) / (1.f + e);
    return copysignf(r, x);
}
__device__ __forceinline__ float fdot2_(half2_t a, half2_t b, float c) {
#if __has_builtin(__builtin_amdgcn_fdot2)
    return __builtin_amdgcn_fdot2(a, b, c, false);
#else
    return c + (float)a.x * (float)b.x + (float)a.y * (float)b.y;
#endif
}

// Tiny prep: cast w1/w2/w_ih_f to f16, sum LSTM biases. grid 1024x256.
__global__ void prep_cast(const float* __restrict__ w1, const float* __restrict__ w2,
                          const float* __restrict__ wih, const float* __restrict__ bih,
                          const float* __restrict__ bhh,
                          _Float16* __restrict__ w1h, _Float16* __restrict__ w2h,
                          _Float16* __restrict__ wihh, float* __restrict__ bsum)
{
    const int i = blockIdx.x * 256 + threadIdx.x;
    if (i < 131072) w1h[i] = (_Float16)w1[i];
    if (i < 65536)  w2h[i] = (_Float16)w2[i];
    if (i < 262144) wihh[i] = (_Float16)wih[i];
    if (i < 1024)   bsum[i] = bih[i] + bhh[i];
}

// x[b][c=512][t=512] fp32 -> xt[b][t][c] f16 (64x64 LDS tiles, coalesced both sides)
__global__ __launch_bounds__(256) void cast_transpose_x(
    const float* __restrict__ x, _Float16* __restrict__ xt)
{
    const int b = blockIdx.z, c0 = blockIdx.y * 64, t0 = blockIdx.x * 64;
    __shared__ float tl[64][68];
    const float* xb = x + (size_t)b * CIN * TT;
    const int tid = threadIdx.x;
    const int lt = (tid & 15) * 4, lc = tid >> 4;
    #pragma unroll
    for (int r = 0; r < 4; ++r) {
        const int c = lc + r * 16;
        float4 v = *(const float4*)(xb + (size_t)(c0 + c) * TT + t0 + lt);
        tl[c][lt] = v.x; tl[c][lt + 1] = v.y; tl[c][lt + 2] = v.z; tl[c][lt + 3] = v.w;
    }
    __syncthreads();
    const int trow = tid >> 2, coff = (tid & 3) * 16;
    _Float16 o[16];
    #pragma unroll
    for (int i = 0; i < 16; ++i) o[i] = (_Float16)tl[coff + i][trow];
    _Float16* dst = xt + (size_t)b * TT * CIN + (size_t)(t0 + trow) * CIN + c0 + coff;
    *(float4*)dst = *(float4*)&o[0];
    *(float4*)(dst + 8) = *(float4*)&o[8];
}

// C[M,N](f16) = op( A[M,K]f16 . B[N,K]f16^T + bias ), K%32==0, M%128==0, N%128==0.
// 128x128 tile, 256 thr = 4 waves of 64x64, v_mfma_f32_16x16x32_f16.
// A/B-frag idx=lane&15, k=quad*8+j; D row=quad*4+reg, col=lane&15 (verified).
template <int RELU, int BIASROW>
__global__ __launch_bounds__(256, 4) void mfma_nt(
    const _Float16* __restrict__ A, const _Float16* __restrict__ B,
    const float* __restrict__ bias, _Float16* __restrict__ C,
    int M, int N, int K, long sA, long sB, long sC)
{
    __shared__ __align__(16) char smem[34816];
    _Float16 (*As)[40] = (_Float16(*)[40])smem;
    _Float16 (*Bs)[40] = (_Float16(*)[40])(smem + 10240);
    float (*Ct)[132] = (float(*)[132])smem;   // 64 x 132 fp32 (union w/ stage)

    const int nb = blockIdx.z;
    A += (size_t)nb * sA; B += (size_t)nb * sB; C += (size_t)nb * sC;
    const int m0 = blockIdx.y * 128, n0 = blockIdx.x * 128;
    const int tid = threadIdx.x;
    const int wave = tid >> 6, lane = tid & 63;
    const int quad = lane >> 4, l15 = lane & 15;
    const int wm = (wave >> 1) * 64, wn = (wave & 1) * 64;
    const int srow = tid >> 1, sko = (tid & 1) * 16;   // staging map

    f32x4_t acc[4][4];
    const f32x4_t zz = {0.f, 0.f, 0.f, 0.f};
    #pragma unroll
    for (int i = 0; i < 4; ++i)
        #pragma unroll
        for (int j = 0; j < 4; ++j) acc[i][j] = zz;

    for (int k0 = 0; k0 < K; k0 += 32) {
        {   // stage A,B tiles: 128 rows x 32 k each; thread = 16 f16 per tile
            const float4* ga = (const float4*)(A + (size_t)(m0 + srow) * K + k0 + sko);
            float4 a0 = ga[0], a1 = ga[1];
            const float4* gb = (const float4*)(B + (size_t)(n0 + srow) * K + k0 + sko);
            float4 b0 = gb[0], b1 = gb[1];
            *(float4*)&As[srow][sko] = a0; *(float4*)&As[srow][sko + 8] = a1;
            *(float4*)&Bs[srow][sko] = b0; *(float4*)&Bs[srow][sko + 8] = b1;
        }
        __syncthreads();
        half8_t af[4], bf[4];
        #pragma unroll
        for (int i = 0; i < 4; ++i) af[i] = *(const half8_t*)&As[wm + i * 16 + l15][quad * 8];
        #pragma unroll
        for (int j = 0; j < 4; ++j) bf[j] = *(const half8_t*)&Bs[wn + j * 16 + l15][quad * 8];
        #pragma unroll
        for (int i = 0; i < 4; ++i)
            #pragma unroll
            for (int j = 0; j < 4; ++j)
                acc[i][j] = __builtin_amdgcn_mfma_f32_16x16x32_f16(af[i], bf[j], acc[i][j], 0, 0, 0);
        __syncthreads();
    }

    // epilogue: bounce 64-row halves through LDS (fp32), bias+relu+cvt, coalesced store
    const int trow = tid >> 2, coff = (tid & 3) * 32;
    float bcol[32];
    if (!BIASROW) {
        #pragma unroll
        for (int i = 0; i < 8; ++i)
            *(float4*)&bcol[i * 4] = *(const float4*)&bias[n0 + coff + i * 4];
    }
    #pragma unroll
    for (int p = 0; p < 2; ++p) {
        if (p) __syncthreads();
        if ((wave >> 1) == p) {
            #pragma unroll
            for (int mi = 0; mi < 4; ++mi)
                #pragma unroll
                for (int ni = 0; ni < 4; ++ni)
                    #pragma unroll
                    for (int r = 0; r < 4; ++r)
                        Ct[mi * 16 + quad * 4 + r][wn + ni * 16 + l15] = acc[mi][ni][r];
        }
        __syncthreads();
        float brow = 0.f;
        if (BIASROW) brow = bias[m0 + p * 64 + trow];
        float vv[32];
        #pragma unroll
        for (int i = 0; i < 8; ++i) *(float4*)&vv[i * 4] = *(float4*)&Ct[trow][coff + i * 4];
        _Float16 o[32];
        #pragma unroll
        for (int i = 0; i < 32; ++i) {
            float v = vv[i] + (BIASROW ? brow : bcol[i]);
            if (RELU) v = fmaxf(v, 0.f);
            o[i] = (_Float16)v;
        }
        _Float16* dst = C + (size_t)(m0 + p * 64 + trow) * N + n0 + coff;
        #pragma unroll
        for (int i = 0; i < 4; ++i) *(float4*)(dst + i * 8) = *(float4*)&o[i * 8];
    }
}

// Forward LSTM scan v10 = v5 skeleton + L2-ATOMIC fast exchange.
// v9 post-mortem: sc0 flagged loads never saw the partner's line (WRITE_SIZE
// unchanged at 74MB proves every publish went via MALL); cache-flag semantics
// are the wrong primitive. v10 uses ATOMICS: global atomics execute AT the L2
// (never cached in L1 -> no staleness). Workgroup-scope __hip_atomic_* compile
// to plain global_atomic (no sc1) -> executed at this XCD's L2 (~250cy RT);
// agent scope (sc1) is the MALL path (v5, ~2500cy). Pair (g, g+128) is
// same-XCD under round-robin dispatch (g == g+128 mod 8) -> partner's L2-swap
// and my L2-fetch_add(0) meet at the same physical L2.
// Mapping-independence (G16): DUAL publish (fast L2 atomic + agent store);
// poll = 2 fast atomic probes then alternate fast/slow. Cross-XCD placement ->
// fast tags never match (atomics land in disjoint L2s) -> proven slow path
// carries; bounded +~500cy/step downside. Monotone tags 1..511; 0 never
// matches (xbF zeroed in lstm_back_last); ABA-safe as in v5.
__global__ __launch_bounds__(1024, 4) void lstm_scan10(
    const _Float16* __restrict__ xg, const float* __restrict__ whh,
    float* __restrict__ out, unsigned long long* __restrict__ xb,
    unsigned long long* __restrict__ xbF)
{
    const int tid = threadIdx.x;
    const int bid = blockIdx.x;
    const int is_hi = (bid >= 128) ? 1 : 0;
    const int g = is_hi ? bid - 128 : bid;
    const int q4 = tid >> 8;           // K-quarter (wave-uniform)
    const int s = tid & 255;
    const int u = s & 127;
    const int rowA = (s >> 7) * 256 + is_hi * 128 + u;  // gate 0/1 row
    const int rowB = rowA + 512;                        // gate 2/3 row

    __shared__ __align__(16) unsigned int hsh[128];  // h: 256 f16 (lo|hi)
    __shared__ float psh[2048];                      // [quarter][512 rows]

    half2_t wA[32], wB[32];
    {
        const float4* pa = (const float4*)(whh + (size_t)rowA * 256 + q4 * 64);
        const float4* pb = (const float4*)(whh + (size_t)rowB * 256 + q4 * 64);
        #pragma unroll
        for (int k = 0; k < 16; ++k) {
            float4 a = pa[k], b = pb[k];
            wA[2 * k + 0] = half2_t{(_Float16)a.x, (_Float16)a.y};
            wA[2 * k + 1] = half2_t{(_Float16)a.z, (_Float16)a.w};
            wB[2 * k + 0] = half2_t{(_Float16)b.x, (_Float16)b.y};
            wB[2 * k + 1] = half2_t{(_Float16)b.z, (_Float16)b.w};
        }
    }
    if (tid < 128) hsh[tid] = 0u;
    const _Float16* xgb = xg + (size_t)g * TT * GG;
    float xA = 0.f, xB = 0.f;
    if (q4 == 0) { xA = (float)xgb[rowA]; xB = (float)xgb[rowB]; }
    float c0 = 0.f, c1 = 0.f, hk0 = 0.f, hk1 = 0.f;   // wave-0 lane state
    __syncthreads();

    for (int t = 0; t < TT; ++t) {
        const float vA = xA, vB = xB;
        if (q4 == 0 && t < TT - 1) {   // prefetch next xg behind the dot loop
            xA = (float)xgb[(size_t)(t + 1) * GG + rowA];
            xB = (float)xgb[(size_t)(t + 1) * GG + rowB];
        }
        float aA0 = 0.f, aA1 = 0.f, aB0 = 0.f, aB1 = 0.f;
        const float4* hp = (const float4*)hsh + q4 * 8;
        #pragma unroll
        for (int kk = 0; kk < 8; ++kk) {
            const float4 hv = hp[kk];   // wave-uniform address -> broadcast
            const half2_t h0 = __builtin_bit_cast(half2_t, hv.x);
            const half2_t h1 = __builtin_bit_cast(half2_t, hv.y);
            const half2_t h2 = __builtin_bit_cast(half2_t, hv.z);
            const half2_t h3 = __builtin_bit_cast(half2_t, hv.w);
            aA0 = fdot2_(wA[4 * kk + 0], h0, aA0);
            aA1 = fdot2_(wA[4 * kk + 1], h1, aA1);
            aA0 = fdot2_(wA[4 * kk + 2], h2, aA0);
            aA1 = fdot2_(wA[4 * kk + 3], h3, aA1);
            aB0 = fdot2_(wB[4 * kk + 0], h0, aB0);
            aB1 = fdot2_(wB[4 * kk + 1], h1, aB1);
            aB0 = fdot2_(wB[4 * kk + 2], h2, aB0);
            aB1 = fdot2_(wB[4 * kk + 3], h3, aB1);
        }
        psh[q4 * 512 + s]       = aA0 + aA1 + vA;
        psh[q4 * 512 + 256 + s] = aB0 + aB1 + vB;
        __syncthreads();               // B1: partials staged; h reads done
        if (tid < 64) {                // wave 0 finishes units 2l, 2l+1
            const int l = tid;
            float2 gate[4];
            #pragma unroll
            for (int gg = 0; gg < 4; ++gg) {
                float2 sum = {0.f, 0.f};
                #pragma unroll
                for (int qq = 0; qq < 4; ++qq) {
                    const float2 v = *(const float2*)&psh[qq * 512 + gg * 128 + 2 * l];
                    sum.x += v.x; sum.y += v.y;
                }
                gate[gg] = sum;
            }
            const float i0 = sigf(gate[0].x), i1 = sigf(gate[0].y);
            const float f0 = sigf(gate[1].x), f1 = sigf(gate[1].y);
            const float g0 = tanhf_(gate[2].x), g1 = tanhf_(gate[2].y);
            const float o0 = sigf(gate[3].x), o1 = sigf(gate[3].y);
            c0 = f0 * c0 + i0 * g0;  hk0 = o0 * tanhf_(c0);
            c1 = f1 * c1 + i1 * g1;  hk1 = o1 * tanhf_(c1);
            const unsigned int u0 =
                (unsigned int)__builtin_bit_cast(unsigned short, (_Float16)hk0);
            const unsigned int u1 =
                (unsigned int)__builtin_bit_cast(unsigned short, (_Float16)hk1);
            hsh[is_hi * 64 + l] = u0 | (u1 << 16);   // own half into LDS
            if (t < TT - 1) {
                const unsigned int tg = (unsigned int)(t + 1) << 16;
                const unsigned long long pk =
                    ((unsigned long long)(tg | u1) << 32) | (unsigned long long)(tg | u0);
                // fast publish: atomic executed at this XCD's L2 (no sc1)
                __hip_atomic_exchange(&xbF[((size_t)g * 2 + is_hi) * 64 + l], pk,
                                      __ATOMIC_RELAXED, __HIP_MEMORY_SCOPE_WORKGROUP);
                // slow publish: agent scope (MALL) — always-correct fallback
                __hip_atomic_store(&xb[((size_t)g * 2 + is_hi) * 64 + l], pk,
                                   __ATOMIC_RELAXED, __HIP_MEMORY_SCOPE_AGENT);
                asm volatile("" ::: "memory");
                unsigned long long* fsrc =
                    &xbF[((size_t)g * 2 + (1 - is_hi)) * 64 + l];
                const unsigned long long* ssrc =
                    &xb[((size_t)g * 2 + (1 - is_hi)) * 64 + l];
                const unsigned int want = (unsigned int)(t + 1);
                unsigned long long v;
                int spin = 0;
                for (;;) {
                    // fast probe: L2-executed atomic read (fetch_add 0)
                    v = __hip_atomic_fetch_add(fsrc, 0ull, __ATOMIC_RELAXED,
                                               __HIP_MEMORY_SCOPE_WORKGROUP);
                    if ((((v >> 16) & 0xFFFFu) == want) &&
                        ((unsigned)(v >> 48) == want)) break;
                    if (spin >= 2) {   // cross-XCD (or late): proven slow path
                        v = __hip_atomic_load(ssrc, __ATOMIC_RELAXED,
                                              __HIP_MEMORY_SCOPE_AGENT);
                        if ((((v >> 16) & 0xFFFFu) == want) &&
                            ((unsigned)(v >> 48) == want)) break;
                        __builtin_amdgcn_s_sleep(1);
                    }
                    ++spin;
                }
                hsh[(1 - is_hi) * 64 + l] =
                    (unsigned int)(v & 0xFFFFu) |
                    ((unsigned int)((v >> 32) & 0xFFFFu) << 16);
            }
        }
        __syncthreads();               // B2: h (own + partner) visible to all
    }
    if (tid < 64) {
        out[(size_t)g * 512 + is_hi * 128 + 2 * tid + 0] = hk0;
        out[(size_t)g * 512 + is_hi * 128 + 2 * tid + 1] = hk1;
    }
}

// Backward-direction LSTM last step (h=c=0): needs only seq[:,T-1,:].
// Also zeroes the fast-exchange buffer xbF (16384 u64 across 32768 threads)
// before lstm_scan10 runs — this region is the dead y1t space.
__global__ __launch_bounds__(256) void lstm_back_last(
    const _Float16* __restrict__ y2h, const float* __restrict__ wih,
    const float* __restrict__ bih, const float* __restrict__ bhh,
    float* __restrict__ out, unsigned long long* __restrict__ xbF)
{
    const int b = blockIdx.x;
    const int t = threadIdx.x;
    const int gi = b * 256 + t;
    if (gi < 16384) xbF[gi] = 0ull;    // tag 0 never matches t+1 in [1,511]
    __shared__ float s[256];
    s[t] = (float)y2h[(size_t)b * (HID * TT) + (TT - 1) * HID + t];
    __syncthreads();
    float acc[4];
    #pragma unroll
    for (int q = 0; q < 4; ++q) acc[q] = bih[t + q * 256] + bhh[t + q * 256];
    #pragma unroll
    for (int q = 0; q < 4; ++q) {
        const float* w = wih + (size_t)(t + q * 256) * 256;
        float a = acc[q];
        for (int k = 0; k < 256; k += 4) {
            const float4 w4 = *(const float4*)&w[k];
            const float4 h4 = *(const float4*)&s[k];
            a += w4.x * h4.x; a += w4.y * h4.y;
            a += w4.z * h4.z; a += w4.w * h4.w;
        }
        acc[q] = a;
    }
    const float i = sigf(acc[0]);
    const float g = tanhf_(acc[2]), o = sigf(acc[3]);
    const float c = i * g;           // c_prev = 0, forget path vanishes
    const float h = o * tanhf_(c);
    out[(size_t)b * 512 + 256 + t] = h;
}

extern "C" void kernel_launch(void* const* d_in, const int* in_sizes, int n_in,
                              void* d_out, int out_size, void* d_ws, size_t ws_size,
                              hipStream_t stream) {
    const float* x      = (const float*)d_in[0];
    const float* w1     = (const float*)d_in[1];
    const float* b1     = (const float*)d_in[2];
    const float* w2     = (const float*)d_in[3];
    const float* b2     = (const float*)d_in[4];
    const float* w_ih_f = (const float*)d_in[5];
    const float* w_hh_f = (const float*)d_in[6];
    const float* b_ih_f = (const float*)d_in[7];
    const float* b_hh_f = (const float*)d_in[8];
    const float* w_ih_b = (const float*)d_in[9];
    // d_in[10] = w_hh_b: provably unused (only first reversed step reaches output)
    const float* b_ih_b = (const float*)d_in[11];
    const float* b_hh_b = (const float*)d_in[12];
    float* out = (float*)d_out;

    // Workspace layout (bytes):
    //   xgh  f16 [65536][1024] :         0 .. 134217728
    //   xt   f16 [128][512][512]: 134217728 .. 201326592
    //   y1t  f16 [128][512][256]: 201326592 .. 234881024   (= y1^T per batch)
    //     (first 131072 B of y1t reused as xbF after conv2 — zeroed in back_last)
    //   y2h  f16 [128][256][512]: 234881024 .. 268435456   (canonical = seq flat)
    //   w1h  f16 131072        : 268435456 .. 268697600
    //   w2h  f16 65536         : 268697600 .. 268828672
    //   wihh f16 262144        : 268828672 .. 269352960
    //   bsum f32 1024          : 269352960 .. 269357056
    //   xb   u64 16384         : 269357056 .. 269488128   (tagged h exchange, MALL)
    char* ws = (char*)d_ws;
    _Float16* xgh  = (_Float16*)(ws);
    _Float16* xt   = (_Float16*)(ws + 134217728);
    _Float16* y1t  = (_Float16*)(ws + 201326592);
    _Float16* y2h  = (_Float16*)(ws + 234881024);
    _Float16* w1h  = (_Float16*)(ws + 268435456);
    _Float16* w2h  = (_Float16*)(ws + 268697600);
    _Float16* wihh = (_Float16*)(ws + 268828672);
    float*    bsum = (float*)   (ws + 269352960);
    unsigned long long* xb  = (unsigned long long*)(ws + 269357056);
    unsigned long long* xbF = (unsigned long long*)(ws + 201326592); // dead y1t

    prep_cast<<<1024, 256, 0, stream>>>(w1, w2, w_ih_f, b_ih_f, b_hh_f,
                                        w1h, w2h, wihh, bsum);
    cast_transpose_x<<<dim3(8, 8, BATCH), 256, 0, stream>>>(x, xt);
    // conv1: y1t[b][t][m1] = relu( xt[b][t][:] . w1h[m1][:] + b1[m1] )   (bias on col)
    mfma_nt<1, 0><<<dim3(2, 4, BATCH), 256, 0, stream>>>(
        xt, w1h, b1, y1t, 512, 256, 512, 512L * 512, 0, 512L * 256);
    // conv2: y2h[b][m2][t] = relu( w2h[m2][:] . y1t[b][t][:] + b2[m2] )  (bias on row)
    mfma_nt<1, 1><<<dim3(4, 2, BATCH), 256, 0, stream>>>(
        w2h, y1t, b2, y2h, 256, 512, 256, 0, 512L * 256, 256L * 512);
    // xg: xgh[r][g] = y2h-flat[r][:] . wihh[g][:] + bsum[g]              (bias on col)
    mfma_nt<0, 0><<<dim3(8, 512, 1), 256, 0, stream>>>(
        y2h, wihh, bsum, xgh, 65536, 1024, 256, 0, 0, 0);
    // backward last step (writes out[:, 256:512)) + zero xbF for the scan
    lstm_back_last<<<BATCH, 256, 0, stream>>>(y2h, w_ih_b, b_ih_b, b_hh_b, out, xbF);
    // forward scan v10 (writes out[:, 0:256))
    lstm_scan10<<<256, 1024, 0, stream>>>(xgh, w_hh_f, out, xb, xbF);
}

// Round 8
// 1305.332 us; speedup vs baseline: 1.4167x; 1.1128x over previous
//
#include <hip/hip_runtime.h>
#include <math.h>

// Sizes fixed by the problem
#define BATCH 128
#define TT 512      // time steps
#define CIN 512
#define HID 256
#define GG 1024     // 4*HID

typedef _Float16 half2_t __attribute__((ext_vector_type(2)));
typedef _Float16 half8_t __attribute__((ext_vector_type(8)));
typedef float f32x4_t __attribute__((ext_vector_type(4)));

__device__ __forceinline__ float sigf(float x) { return 1.f / (1.f + __expf(-x)); }
__device__ __forceinline__ float tanhf_(float x) {
    float a = fabsf(x);
    float e = __expf(-2.f * a);
    float r = (1.f - e) / (1.f + e);
    return copysignf(r, x);
}
__device__ __forceinline__ float fdot2_(half2_t a, half2_t b, float c) {
#if __has_builtin(__builtin_amdgcn_fdot2)
    return __builtin_amdgcn_fdot2(a, b, c, false);
#else
    return c + (float)a.x * (float)b.x + (float)a.y * (float)b.y;
#endif
}

// Tiny prep: cast w1/w2/w_ih_f to f16, sum LSTM biases. grid 1024x256.
__global__ void prep_cast(const float* __restrict__ w1, const float* __restrict__ w2,
                          const float* __restrict__ wih, const float* __restrict__ bih,
                          const float* __restrict__ bhh,
                          _Float16* __restrict__ w1h, _Float16* __restrict__ w2h,
                          _Float16* __restrict__ wihh, float* __restrict__ bsum)
{
    const int i = blockIdx.x * 256 + threadIdx.x;
    if (i < 131072) w1h[i] = (_Float16)w1[i];
    if (i < 65536)  w2h[i] = (_Float16)w2[i];
    if (i < 262144) wihh[i] = (_Float16)wih[i];
    if (i < 1024)   bsum[i] = bih[i] + bhh[i];
}

// x[b][c=512][t=512] fp32 -> xt[b][t][c] f16 (64x64 LDS tiles, coalesced both sides)
__global__ __launch_bounds__(256) void cast_transpose_x(
    const float* __restrict__ x, _Float16* __restrict__ xt)
{
    const int b = blockIdx.z, c0 = blockIdx.y * 64, t0 = blockIdx.x * 64;
    __shared__ float tl[64][68];
    const float* xb = x + (size_t)b * CIN * TT;
    const int tid = threadIdx.x;
    const int lt = (tid & 15) * 4, lc = tid >> 4;
    #pragma unroll
    for (int r = 0; r < 4; ++r) {
        const int c = lc + r * 16;
        float4 v = *(const float4*)(xb + (size_t)(c0 + c) * TT + t0 + lt);
        tl[c][lt] = v.x; tl[c][lt + 1] = v.y; tl[c][lt + 2] = v.z; tl[c][lt + 3] = v.w;
    }
    __syncthreads();
    const int trow = tid >> 2, coff = (tid & 3) * 16;
    _Float16 o[16];
    #pragma unroll
    for (int i = 0; i < 16; ++i) o[i] = (_Float16)tl[coff + i][trow];
    _Float16* dst = xt + (size_t)b * TT * CIN + (size_t)(t0 + trow) * CIN + c0 + coff;
    *(float4*)dst = *(float4*)&o[0];
    *(float4*)(dst + 8) = *(float4*)&o[8];
}

// C[M,N](f16) = op( A[M,K]f16 . B[N,K]f16^T + bias ), K%32==0, M%128==0, N%128==0.
// 128x128 tile, 256 thr = 4 waves of 64x64, v_mfma_f32_16x16x32_f16.
// A/B-frag idx=lane&15, k=quad*8+j; D row=quad*4+reg, col=lane&15 (verified).
template <int RELU, int BIASROW>
__global__ __launch_bounds__(256, 4) void mfma_nt(
    const _Float16* __restrict__ A, const _Float16* __restrict__ B,
    const float* __restrict__ bias, _Float16* __restrict__ C,
    int M, int N, int K, long sA, long sB, long sC)
{
    __shared__ __align__(16) char smem[34816];
    _Float16 (*As)[40] = (_Float16(*)[40])smem;
    _Float16 (*Bs)[40] = (_Float16(*)[40])(smem + 10240);
    float (*Ct)[132] = (float(*)[132])smem;   // 64 x 132 fp32 (union w/ stage)

    const int nb = blockIdx.z;
    A += (size_t)nb * sA; B += (size_t)nb * sB; C += (size_t)nb * sC;
    const int m0 = blockIdx.y * 128, n0 = blockIdx.x * 128;
    const int tid = threadIdx.x;
    const int wave = tid >> 6, lane = tid & 63;
    const int quad = lane >> 4, l15 = lane & 15;
    const int wm = (wave >> 1) * 64, wn = (wave & 1) * 64;
    const int srow = tid >> 1, sko = (tid & 1) * 16;   // staging map

    f32x4_t acc[4][4];
    const f32x4_t zz = {0.f, 0.f, 0.f, 0.f};
    #pragma unroll
    for (int i = 0; i < 4; ++i)
        #pragma unroll
        for (int j = 0; j < 4; ++j) acc[i][j] = zz;

    for (int k0 = 0; k0 < K; k0 += 32) {
        {   // stage A,B tiles: 128 rows x 32 k each; thread = 16 f16 per tile
            const float4* ga = (const float4*)(A + (size_t)(m0 + srow) * K + k0 + sko);
            float4 a0 = ga[0], a1 = ga[1];
            const float4* gb = (const float4*)(B + (size_t)(n0 + srow) * K + k0 + sko);
            float4 b0 = gb[0], b1 = gb[1];
            *(float4*)&As[srow][sko] = a0; *(float4*)&As[srow][sko + 8] = a1;
            *(float4*)&Bs[srow][sko] = b0; *(float4*)&Bs[srow][sko + 8] = b1;
        }
        __syncthreads();
        half8_t af[4], bf[4];
        #pragma unroll
        for (int i = 0; i < 4; ++i) af[i] = *(const half8_t*)&As[wm + i * 16 + l15][quad * 8];
        #pragma unroll
        for (int j = 0; j < 4; ++j) bf[j] = *(const half8_t*)&Bs[wn + j * 16 + l15][quad * 8];
        #pragma unroll
        for (int i = 0; i < 4; ++i)
            #pragma unroll
            for (int j = 0; j < 4; ++j)
                acc[i][j] = __builtin_amdgcn_mfma_f32_16x16x32_f16(af[i], bf[j], acc[i][j], 0, 0, 0);
        __syncthreads();
    }

    // epilogue: bounce 64-row halves through LDS (fp32), bias+relu+cvt, coalesced store
    const int trow = tid >> 2, coff = (tid & 3) * 32;
    float bcol[32];
    if (!BIASROW) {
        #pragma unroll
        for (int i = 0; i < 8; ++i)
            *(float4*)&bcol[i * 4] = *(const float4*)&bias[n0 + coff + i * 4];
    }
    #pragma unroll
    for (int p = 0; p < 2; ++p) {
        if (p) __syncthreads();
        if ((wave >> 1) == p) {
            #pragma unroll
            for (int mi = 0; mi < 4; ++mi)
                #pragma unroll
                for (int ni = 0; ni < 4; ++ni)
                    #pragma unroll
                    for (int r = 0; r < 4; ++r)
                        Ct[mi * 16 + quad * 4 + r][wn + ni * 16 + l15] = acc[mi][ni][r];
        }
        __syncthreads();
        float brow = 0.f;
        if (BIASROW) brow = bias[m0 + p * 64 + trow];
        float vv[32];
        #pragma unroll
        for (int i = 0; i < 8; ++i) *(float4*)&vv[i * 4] = *(float4*)&Ct[trow][coff + i * 4];
        _Float16 o[32];
        #pragma unroll
        for (int i = 0; i < 32; ++i) {
            float v = vv[i] + (BIASROW ? brow : bcol[i]);
            if (RELU) v = fmaxf(v, 0.f);
            o[i] = (_Float16)v;
        }
        _Float16* dst = C + (size_t)(m0 + p * 64 + trow) * N + n0 + coff;
        #pragma unroll
        for (int i = 0; i < 4; ++i) *(float4*)(dst + i * 8) = *(float4*)&o[i * 8];
    }
}

// Forward LSTM scan v11 = v5 skeleton + parity mailbox + PIPELINED poll.
// v6-v10 lessons: weights must be reg-resident (per-CU load BW ~60-100 B/cy)
// -> 2-block split forced; mailbox always round-trips the memory-side fabric
// (scope tricks don't help: v10's WRITE_SIZE doubling proved atomics execute
// memory-side at any scope). v5's exposed cost = SERIAL poll: each probe is
// load->vmcnt(0)->check->sleep, so discovery lags arrival by 1-2 full load
// latencies. v11 keeps 3 probe pairs in flight (asm, s_waitcnt vmcnt(4));
// discovery granularity ~= probe issue gap (~50cy) instead of ~Lr.
// Each 32-bit word is self-validating (tag in bits 16-31) -> dword probes OK.
// Bounded fallback to v5's proven atomic-load loop after 24 iterations.
// PARITY mailbox [2][256][64] (slot = tag&1) fixes a latent v5 livelock:
// partner's t+2 publish could overwrite t+1 before a preempted reader sees
// it; with parity, the t+3 write to my slot requires my t+2 publish, which
// requires this very read -> value can't be lost. Zeroed in lstm_back_last
// (dead y1t region); tag 0 never matches t+1 in [1,511].
__global__ __launch_bounds__(1024, 4) void lstm_scan11(
    const _Float16* __restrict__ xg, const float* __restrict__ whh,
    float* __restrict__ out, unsigned long long* __restrict__ mb)
{
    const int tid = threadIdx.x;
    const int bid = blockIdx.x;
    const int is_hi = (bid >= 128) ? 1 : 0;
    const int g = is_hi ? bid - 128 : bid;
    const int q4 = tid >> 8;           // K-quarter (wave-uniform)
    const int s = tid & 255;
    const int u = s & 127;
    const int rowA = (s >> 7) * 256 + is_hi * 128 + u;  // gate 0/1 row
    const int rowB = rowA + 512;                        // gate 2/3 row

    __shared__ __align__(16) unsigned int hsh[128];  // h: 256 f16 (lo|hi)
    __shared__ float psh[2048];                      // [quarter][512 rows]

    half2_t wA[32], wB[32];
    {
        const float4* pa = (const float4*)(whh + (size_t)rowA * 256 + q4 * 64);
        const float4* pb = (const float4*)(whh + (size_t)rowB * 256 + q4 * 64);
        #pragma unroll
        for (int k = 0; k < 16; ++k) {
            float4 a = pa[k], b = pb[k];
            wA[2 * k + 0] = half2_t{(_Float16)a.x, (_Float16)a.y};
            wA[2 * k + 1] = half2_t{(_Float16)a.z, (_Float16)a.w};
            wB[2 * k + 0] = half2_t{(_Float16)b.x, (_Float16)b.y};
            wB[2 * k + 1] = half2_t{(_Float16)b.z, (_Float16)b.w};
        }
    }
    if (tid < 128) hsh[tid] = 0u;
    const _Float16* xgb = xg + (size_t)g * TT * GG;
    float xA = 0.f, xB = 0.f;
    if (q4 == 0) { xA = (float)xgb[rowA]; xB = (float)xgb[rowB]; }
    float c0 = 0.f, c1 = 0.f, hk0 = 0.f, hk1 = 0.f;   // wave-0 lane state
    __syncthreads();

    for (int t = 0; t < TT; ++t) {
        const float vA = xA, vB = xB;
        if (q4 == 0 && t < TT - 1) {   // prefetch next xg behind the dot loop
            xA = (float)xgb[(size_t)(t + 1) * GG + rowA];
            xB = (float)xgb[(size_t)(t + 1) * GG + rowB];
        }
        float aA0 = 0.f, aA1 = 0.f, aB0 = 0.f, aB1 = 0.f;
        const float4* hp = (const float4*)hsh + q4 * 8;
        #pragma unroll
        for (int kk = 0; kk < 8; ++kk) {
            const float4 hv = hp[kk];   // wave-uniform address -> broadcast
            const half2_t h0 = __builtin_bit_cast(half2_t, hv.x);
            const half2_t h1 = __builtin_bit_cast(half2_t, hv.y);
            const half2_t h2 = __builtin_bit_cast(half2_t, hv.z);
            const half2_t h3 = __builtin_bit_cast(half2_t, hv.w);
            aA0 = fdot2_(wA[4 * kk + 0], h0, aA0);
            aA1 = fdot2_(wA[4 * kk + 1], h1, aA1);
            aA0 = fdot2_(wA[4 * kk + 2], h2, aA0);
            aA1 = fdot2_(wA[4 * kk + 3], h3, aA1);
            aB0 = fdot2_(wB[4 * kk + 0], h0, aB0);
            aB1 = fdot2_(wB[4 * kk + 1], h1, aB1);
            aB0 = fdot2_(wB[4 * kk + 2], h2, aB0);
            aB1 = fdot2_(wB[4 * kk + 3], h3, aB1);
        }
        psh[q4 * 512 + s]       = aA0 + aA1 + vA;
        psh[q4 * 512 + 256 + s] = aB0 + aB1 + vB;
        __syncthreads();               // B1: partials staged; h reads done
        if (tid < 64) {                // wave 0 finishes units 2l, 2l+1
            const int l = tid;
            float2 gate[4];
            #pragma unroll
            for (int gg = 0; gg < 4; ++gg) {
                float2 sum = {0.f, 0.f};
                #pragma unroll
                for (int qq = 0; qq < 4; ++qq) {
                    const float2 v = *(const float2*)&psh[qq * 512 + gg * 128 + 2 * l];
                    sum.x += v.x; sum.y += v.y;
                }
                gate[gg] = sum;
            }
            const float i0 = sigf(gate[0].x), i1 = sigf(gate[0].y);
            const float f0 = sigf(gate[1].x), f1 = sigf(gate[1].y);
            const float g0 = tanhf_(gate[2].x), g1 = tanhf_(gate[2].y);
            const float o0 = sigf(gate[3].x), o1 = sigf(gate[3].y);
            c0 = f0 * c0 + i0 * g0;  hk0 = o0 * tanhf_(c0);
            c1 = f1 * c1 + i1 * g1;  hk1 = o1 * tanhf_(c1);
            const unsigned int u0 =
                (unsigned int)__builtin_bit_cast(unsigned short, (_Float16)hk0);
            const unsigned int u1 =
                (unsigned int)__builtin_bit_cast(unsigned short, (_Float16)hk1);
            if (t < TT - 1) {
                const unsigned int want = (unsigned int)(t + 1);
                const unsigned int tg = want << 16;
                const unsigned long long pk =
                    ((unsigned long long)(tg | u1) << 32) | (unsigned long long)(tg | u0);
                const size_t par = (size_t)(want & 1u) * 16384;
                // publish own half to parity slot (agent scope) ASAP
                __hip_atomic_store(&mb[par + ((size_t)g * 2 + is_hi) * 64 + l], pk,
                                   __ATOMIC_RELAXED, __HIP_MEMORY_SCOPE_AGENT);
                asm volatile("" ::: "memory");
                hsh[is_hi * 64 + l] = u0 | (u1 << 16);   // own half into LDS
                // ---- pipelined poll: 3 dword-pair probes in flight ----
                const unsigned long long srcaddr = (unsigned long long)
                    &mb[par + ((size_t)g * 2 + (1 - is_hi)) * 64 + l];
                unsigned int r0, r1, hit;
                {
                    unsigned int pa0, pa1, pb0, pb1, pc0, pc1, t0, t1, cnt;
                    asm volatile(
                        "global_load_dword %[a0], %[ad], off sc1\n\t"
                        "global_load_dword %[a1], %[ad], off offset:4 sc1\n\t"
                        "global_load_dword %[b0], %[ad], off sc1\n\t"
                        "global_load_dword %[b1], %[ad], off offset:4 sc1\n\t"
                        "global_load_dword %[c0], %[ad], off sc1\n\t"
                        "global_load_dword %[c1], %[ad], off offset:4 sc1\n\t"
                        "s_mov_b32 %[cnt], 0\n"
                        "PL%=:\n\t"
                        "s_waitcnt vmcnt(4)\n\t"
                        "v_lshrrev_b32 %[t0], 16, %[a0]\n\t"
                        "v_lshrrev_b32 %[t1], 16, %[a1]\n\t"
                        "v_cmp_ne_u32 vcc, %[t0], %[wt]\n\t"
                        "s_cbranch_vccnz MA%=\n\t"
                        "v_cmp_ne_u32 vcc, %[t1], %[wt]\n\t"
                        "s_cbranch_vccnz MA%=\n\t"
                        "v_mov_b32 %[r0], %[a0]\n\t"
                        "v_mov_b32 %[r1], %[a1]\n\t"
                        "s_mov_b32 %[hit], 1\n\t"
                        "s_branch PD%=\n"
                        "MA%=:\n\t"
                        "global_load_dword %[a0], %[ad], off sc1\n\t"
                        "global_load_dword %[a1], %[ad], off offset:4 sc1\n\t"
                        "s_waitcnt vmcnt(4)\n\t"
                        "v_lshrrev_b32 %[t0], 16, %[b0]\n\t"
                        "v_lshrrev_b32 %[t1], 16, %[b1]\n\t"
                        "v_cmp_ne_u32 vcc, %[t0], %[wt]\n\t"
                        "s_cbranch_vccnz MB%=\n\t"
                        "v_cmp_ne_u32 vcc, %[t1], %[wt]\n\t"
                        "s_cbranch_vccnz MB%=\n\t"
                        "v_mov_b32 %[r0], %[b0]\n\t"
                        "v_mov_b32 %[r1], %[b1]\n\t"
                        "s_mov_b32 %[hit], 1\n\t"
                        "s_branch PD%=\n"
                        "MB%=:\n\t"
                        "global_load_dword %[b0], %[ad], off sc1\n\t"
                        "global_load_dword %[b1], %[ad], off offset:4 sc1\n\t"
                        "s_waitcnt vmcnt(4)\n\t"
                        "v_lshrrev_b32 %[t0], 16, %[c0]\n\t"
                        "v_lshrrev_b32 %[t1], 16, %[c1]\n\t"
                        "v_cmp_ne_u32 vcc, %[t0], %[wt]\n\t"
                        "s_cbranch_vccnz MC%=\n\t"
                        "v_cmp_ne_u32 vcc, %[t1], %[wt]\n\t"
                        "s_cbranch_vccnz MC%=\n\t"
                        "v_mov_b32 %[r0], %[c0]\n\t"
                        "v_mov_b32 %[r1], %[c1]\n\t"
                        "s_mov_b32 %[hit], 1\n\t"
                        "s_branch PD%=\n"
                        "MC%=:\n\t"
                        "global_load_dword %[c0], %[ad], off sc1\n\t"
                        "global_load_dword %[c1], %[ad], off offset:4 sc1\n\t"
                        "s_add_u32 %[cnt], %[cnt], 1\n\t"
                        "s_cmp_lt_u32 %[cnt], 24\n\t"
                        "s_cbranch_scc1 PL%=\n\t"
                        "s_mov_b32 %[hit], 0\n"
                        "PD%=:\n\t"
                        "s_waitcnt vmcnt(0)"
                        : [a0]"=&v"(pa0), [a1]"=&v"(pa1), [b0]"=&v"(pb0),
                          [b1]"=&v"(pb1), [c0]"=&v"(pc0), [c1]"=&v"(pc1),
                          [t0]"=&v"(t0), [t1]"=&v"(t1),
                          [r0]"=&v"(r0), [r1]"=&v"(r1),
                          [hit]"=&s"(hit), [cnt]"=&s"(cnt)
                        : [ad]"v"(srcaddr), [wt]"v"(want)
                        : "vcc", "memory");
                }
                if (!hit) {   // bounded fallback: v5's proven slow poll
                    const unsigned long long* src =
                        (const unsigned long long*)srcaddr;
                    for (;;) {
                        unsigned long long v = __hip_atomic_load(
                            src, __ATOMIC_RELAXED, __HIP_MEMORY_SCOPE_AGENT);
                        if ((((v >> 16) & 0xFFFFu) == want) &&
                            ((unsigned)(v >> 48) == want)) {
                            r0 = (unsigned int)v;
                            r1 = (unsigned int)(v >> 32);
                            break;
                        }
                        __builtin_amdgcn_s_sleep(1);
                    }
                }
                hsh[(1 - is_hi) * 64 + l] =
                    (r0 & 0xFFFFu) | ((r1 & 0xFFFFu) << 16);
            } else {
                hsh[is_hi * 64 + l] = u0 | (u1 << 16);
            }
        }
        __syncthreads();               // B2: h (own + partner) visible to all
    }
    if (tid < 64) {
        out[(size_t)g * 512 + is_hi * 128 + 2 * tid + 0] = hk0;
        out[(size_t)g * 512 + is_hi * 128 + 2 * tid + 1] = hk1;
    }
}

// Backward-direction LSTM last step (h=c=0): needs only seq[:,T-1,:].
// Also zeroes the parity mailbox (32768 u64 across 32768 threads, one each)
// before lstm_scan11 runs — the region is the dead y1t space.
__global__ __launch_bounds__(256) void lstm_back_last(
    const _Float16* __restrict__ y2h, const float* __restrict__ wih,
    const float* __restrict__ bih, const float* __restrict__ bhh,
    float* __restrict__ out, unsigned long long* __restrict__ mb)
{
    const int b = blockIdx.x;
    const int t = threadIdx.x;
    mb[b * 256 + t] = 0ull;            // tag 0 never matches t+1 in [1,511]
    __shared__ float s[256];
    s[t] = (float)y2h[(size_t)b * (HID * TT) + (TT - 1) * HID + t];
    __syncthreads();
    float acc[4];
    #pragma unroll
    for (int q = 0; q < 4; ++q) acc[q] = bih[t + q * 256] + bhh[t + q * 256];
    #pragma unroll
    for (int q = 0; q < 4; ++q) {
        const float* w = wih + (size_t)(t + q * 256) * 256;
        float a = acc[q];
        for (int k = 0; k < 256; k += 4) {
            const float4 w4 = *(const float4*)&w[k];
            const float4 h4 = *(const float4*)&s[k];
            a += w4.x * h4.x; a += w4.y * h4.y;
            a += w4.z * h4.z; a += w4.w * h4.w;
        }
        acc[q] = a;
    }
    const float i = sigf(acc[0]);
    const float g = tanhf_(acc[2]), o = sigf(acc[3]);
    const float c = i * g;           // c_prev = 0, forget path vanishes
    const float h = o * tanhf_(c);
    out[(size_t)b * 512 + 256 + t] = h;
}

extern "C" void kernel_launch(void* const* d_in, const int* in_sizes, int n_in,
                              void* d_out, int out_size, void* d_ws, size_t ws_size,
                              hipStream_t stream) {
    const float* x      = (const float*)d_in[0];
    const float* w1     = (const float*)d_in[1];
    const float* b1     = (const float*)d_in[2];
    const float* w2     = (const float*)d_in[3];
    const float* b2     = (const float*)d_in[4];
    const float* w_ih_f = (const float*)d_in[5];
    const float* w_hh_f = (const float*)d_in[6];
    const float* b_ih_f = (const float*)d_in[7];
    const float* b_hh_f = (const float*)d_in[8];
    const float* w_ih_b = (const float*)d_in[9];
    // d_in[10] = w_hh_b: provably unused (only first reversed step reaches output)
    const float* b_ih_b = (const float*)d_in[11];
    const float* b_hh_b = (const float*)d_in[12];
    float* out = (float*)d_out;

    // Workspace layout (bytes):
    //   xgh  f16 [65536][1024] :         0 .. 134217728
    //   xt   f16 [128][512][512]: 134217728 .. 201326592
    //   y1t  f16 [128][512][256]: 201326592 .. 234881024   (= y1^T per batch)
    //     (first 262144 B of y1t reused as parity mailbox after conv2)
    //   y2h  f16 [128][256][512]: 234881024 .. 268435456   (canonical = seq flat)
    //   w1h  f16 131072        : 268435456 .. 268697600
    //   w2h  f16 65536         : 268697600 .. 268828672
    //   wihh f16 262144        : 268828672 .. 269352960
    //   bsum f32 1024          : 269352960 .. 269357056
    char* ws = (char*)d_ws;
    _Float16* xgh  = (_Float16*)(ws);
    _Float16* xt   = (_Float16*)(ws + 134217728);
    _Float16* y1t  = (_Float16*)(ws + 201326592);
    _Float16* y2h  = (_Float16*)(ws + 234881024);
    _Float16* w1h  = (_Float16*)(ws + 268435456);
    _Float16* w2h  = (_Float16*)(ws + 268697600);
    _Float16* wihh = (_Float16*)(ws + 268828672);
    float*    bsum = (float*)   (ws + 269352960);
    unsigned long long* mb = (unsigned long long*)(ws + 201326592); // dead y1t

    prep_cast<<<1024, 256, 0, stream>>>(w1, w2, w_ih_f, b_ih_f, b_hh_f,
                                        w1h, w2h, wihh, bsum);
    cast_transpose_x<<<dim3(8, 8, BATCH), 256, 0, stream>>>(x, xt);
    // conv1: y1t[b][t][m1] = relu( xt[b][t][:] . w1h[m1][:] + b1[m1] )   (bias on col)
    mfma_nt<1, 0><<<dim3(2, 4, BATCH), 256, 0, stream>>>(
        xt, w1h, b1, y1t, 512, 256, 512, 512L * 512, 0, 512L * 256);
    // conv2: y2h[b][m2][t] = relu( w2h[m2][:] . y1t[b][t][:] + b2[m2] )  (bias on row)
    mfma_nt<1, 1><<<dim3(4, 2, BATCH), 256, 0, stream>>>(
        w2h, y1t, b2, y2h, 256, 512, 256, 0, 512L * 256, 256L * 512);
    // xg: xgh[r][g] = y2h-flat[r][:] . wihh[g][:] + bsum[g]              (bias on col)
    mfma_nt<0, 0><<<dim3(8, 512, 1), 256, 0, stream>>>(
        y2h, wihh, bsum, xgh, 65536, 1024, 256, 0, 0, 0);
    // backward last step (writes out[:, 256:512)) + zero mailbox for the scan
    lstm_back_last<<<BATCH, 256, 0, stream>>>(y2h, w_ih_b, b_ih_b, b_hh_b, out, mb);
    // forward scan v11 (writes out[:, 0:256))
    lstm_scan11<<<256, 1024, 0, stream>>>(xgh, w_hh_f, out, mb);
}